// Round 1
// baseline (807.482 us; speedup 1.0000x reference)
//
#include <hip/hip_runtime.h>

#define DD 768
#define HDIM 96
#define ATT_SCALE 0.10206207261596575f  // 1/sqrt(96)

typedef float floatx4 __attribute__((ext_vector_type(4)));
typedef __bf16 bf16;
typedef bf16 bf16x8 __attribute__((ext_vector_type(8)));

// ---------------------------------------------------------------- elementwise
__global__ __launch_bounds__(256) void add_kernel(const float* __restrict__ a,
                                                  const float* __restrict__ b,
                                                  float* __restrict__ c, int n4) {
  int i = blockIdx.x * 256 + threadIdx.x;
  int stride = gridDim.x * 256;
  const floatx4* A4 = (const floatx4*)a;
  const floatx4* B4 = (const floatx4*)b;
  floatx4* C4 = (floatx4*)c;
  for (; i < n4; i += stride) C4[i] = A4[i] + B4[i];
}

// ---------------------------------------------------------------- LayerNorm
// one block per row of 768, eps=1e-6, gain g, in-place
__global__ __launch_bounds__(256) void ln_kernel(float* __restrict__ X,
                                                 const float* __restrict__ g) {
  const int row = blockIdx.x;
  float* x = X + (size_t)row * DD;
  const int tid = threadIdx.x;
  float v0 = x[tid], v1 = x[tid + 256], v2 = x[tid + 512];
  float s = v0 + v1 + v2;
  float ss = v0 * v0 + v1 * v1 + v2 * v2;
  for (int o = 32; o > 0; o >>= 1) {
    s += __shfl_xor(s, o);
    ss += __shfl_xor(ss, o);
  }
  __shared__ float red[8];
  const int w = tid >> 6;
  if ((tid & 63) == 0) { red[w] = s; red[4 + w] = ss; }
  __syncthreads();
  s = red[0] + red[1] + red[2] + red[3];
  ss = red[4] + red[5] + red[6] + red[7];
  const float mean = s * (1.0f / DD);
  const float var = ss * (1.0f / DD) - mean * mean;
  const float inv = rsqrtf(var + 1e-6f);
  x[tid]       = (v0 - mean) * inv * g[tid];
  x[tid + 256] = (v1 - mean) * inv * g[tid + 256];
  x[tid + 512] = (v2 - mean) * inv * g[tid + 512];
}

// ---------------------------------------------------------------- GEMM C = A @ W^T (+add)
// A [rows, 768] fp32, W [768, 768] fp32 (row = output channel), C [rows, 768] fp32.
// 64x64 tile per block, 4 waves each 32x32, BK=32, bf16 MFMA with fp32 staging convert.
__global__ __launch_bounds__(256) void gemm_bt(const float* __restrict__ A,
                                               const float* __restrict__ W,
                                               float* __restrict__ C,
                                               const float* __restrict__ addsrc) {
  __shared__ bf16 As[64 * 40];  // stride 40 bf16 = 80B (16B aligned, 2-way max)
  __shared__ bf16 Ws[64 * 40];
  const int tid = threadIdx.x;
  const int lane = tid & 63;
  const int w = tid >> 6;
  const int row0 = blockIdx.x * 64;
  const int col0 = blockIdx.y * 64;
  const int wm = (w & 1) * 32;
  const int wn = (w >> 1) * 32;
  const int fr = lane & 15;
  const int fq = (lane >> 4) * 8;
  const int sr = tid >> 2;
  const int sc = (tid & 3) * 8;
  const float* Arow = A + (size_t)(row0 + sr) * DD + sc;
  const float* Wrow = W + (size_t)(col0 + sr) * DD + sc;
  floatx4 acc00 = {0, 0, 0, 0}, acc01 = {0, 0, 0, 0};
  floatx4 acc10 = {0, 0, 0, 0}, acc11 = {0, 0, 0, 0};
  for (int k0 = 0; k0 < DD; k0 += 32) {
    floatx4 a0 = *(const floatx4*)(Arow + k0);
    floatx4 a1 = *(const floatx4*)(Arow + k0 + 4);
    floatx4 w0 = *(const floatx4*)(Wrow + k0);
    floatx4 w1 = *(const floatx4*)(Wrow + k0 + 4);
    bf16x8 av, wv;
#pragma unroll
    for (int i = 0; i < 4; i++) {
      av[i] = (bf16)a0[i]; av[i + 4] = (bf16)a1[i];
      wv[i] = (bf16)w0[i]; wv[i + 4] = (bf16)w1[i];
    }
    __syncthreads();
    *(bf16x8*)&As[sr * 40 + sc] = av;
    *(bf16x8*)&Ws[sr * 40 + sc] = wv;
    __syncthreads();
    bf16x8 af0 = *(const bf16x8*)&As[(wm + fr) * 40 + fq];
    bf16x8 af1 = *(const bf16x8*)&As[(wm + 16 + fr) * 40 + fq];
    bf16x8 bf0 = *(const bf16x8*)&Ws[(wn + fr) * 40 + fq];
    bf16x8 bf1 = *(const bf16x8*)&Ws[(wn + 16 + fr) * 40 + fq];
    acc00 = __builtin_amdgcn_mfma_f32_16x16x32_bf16(af0, bf0, acc00, 0, 0, 0);
    acc01 = __builtin_amdgcn_mfma_f32_16x16x32_bf16(af0, bf1, acc01, 0, 0, 0);
    acc10 = __builtin_amdgcn_mfma_f32_16x16x32_bf16(af1, bf0, acc10, 0, 0, 0);
    acc11 = __builtin_amdgcn_mfma_f32_16x16x32_bf16(af1, bf1, acc11, 0, 0, 0);
  }
  const int col = lane & 15;
  const int rb = (lane >> 4) * 4;
#pragma unroll
  for (int i = 0; i < 2; i++) {
#pragma unroll
    for (int j = 0; j < 2; j++) {
      floatx4 acc = (i == 0) ? (j == 0 ? acc00 : acc01) : (j == 0 ? acc10 : acc11);
#pragma unroll
      for (int r = 0; r < 4; r++) {
        size_t idx = (size_t)(row0 + wm + i * 16 + rb + r) * DD + (col0 + wn + j * 16 + col);
        float v = acc[r];
        if (addsrc) v += addsrc[idx];
        C[idx] = v;
      }
    }
  }
}

// ---------------------------------------------------------------- fused attention
// Per (t, h, 64-query tile): O = softmax(Q K^T * scale + bias) V, head slice h*96.
// bias = -2 * ||qpos - kpos||^2 (SIGMA=0.5). Q/K/V/O are [T, n, 768] fp32.
__global__ __launch_bounds__(256) void attn_kernel(
    const float* __restrict__ Qb, const float* __restrict__ Kb,
    const float* __restrict__ Vb, float* __restrict__ Ob,
    const float* __restrict__ qpos, int qpos_ts,
    const float* __restrict__ kpos, int kpos_ts,
    int nq, int nk) {
  const int t = blockIdx.z, h = blockIdx.y;
  const int q0 = blockIdx.x * 64;
  const float* Q = Qb + (size_t)t * nq * DD + h * HDIM;
  const float* K = Kb + (size_t)t * nk * DD + h * HDIM;
  const float* V = Vb + (size_t)t * nk * DD + h * HDIM;
  float* O = Ob + (size_t)t * nq * DD + h * HDIM;
  const float* qp = qpos + (size_t)t * qpos_ts;
  const float* kp = kpos + (size_t)t * kpos_ts;

  __shared__ bf16 Ks[64 * 104];  // [n][k] stride 104
  __shared__ bf16 Vt[96 * 72];   // [d][n] stride 72 (transposed for B-operand)
  __shared__ bf16 Ps[64 * 72];   // [m][n] per-wave 16-row strips

  const int tid = threadIdx.x;
  const int w = tid >> 6;
  const int lane = tid & 63;
  const int fr = lane & 15;
  const int quad = lane >> 4;

  // preload Q fragments (A-operand layout: A[m=lane&15][k=quad*8+j]), 3 k-chunks of 32
  bf16x8 qf[3];
  {
    const float* qrow = Q + (size_t)(q0 + w * 16 + fr) * DD;
#pragma unroll
    for (int c = 0; c < 3; c++) {
      floatx4 u0 = *(const floatx4*)(qrow + c * 32 + quad * 8);
      floatx4 u1 = *(const floatx4*)(qrow + c * 32 + quad * 8 + 4);
      bf16x8 q8;
#pragma unroll
      for (int i = 0; i < 4; i++) { q8[i] = (bf16)u0[i]; q8[i + 4] = (bf16)u1[i]; }
      qf[c] = q8;
    }
  }
  // per-lane query positions for the 4 accumulator rows (row = quad*4 + r)
  float qx[4], qy[4];
#pragma unroll
  for (int r = 0; r < 4; r++) {
    int qi = q0 + w * 16 + quad * 4 + r;
    qx[r] = qp[qi * 2];
    qy[r] = qp[qi * 2 + 1];
  }

  float mrow[4], lrow[4];
  floatx4 oacc[6];
#pragma unroll
  for (int r = 0; r < 4; r++) { mrow[r] = -1e30f; lrow[r] = 0.f; }
#pragma unroll
  for (int d = 0; d < 6; d++) oacc[d] = (floatx4){0, 0, 0, 0};

  const int srow = tid >> 2, scol = (tid & 3) * 24;
  const int vn = tid & 63, vd0 = (tid >> 6) * 24;

  for (int n0 = 0; n0 < nk; n0 += 64) {
    __syncthreads();
    // stage K tile [64][96] -> bf16
    {
      const float* kg = K + (size_t)(n0 + srow) * DD + scol;
      bf16* ks = &Ks[srow * 104 + scol];
#pragma unroll
      for (int c = 0; c < 24; c += 8) {
        floatx4 u0 = *(const floatx4*)(kg + c);
        floatx4 u1 = *(const floatx4*)(kg + c + 4);
        bf16x8 k8;
#pragma unroll
        for (int i = 0; i < 4; i++) { k8[i] = (bf16)u0[i]; k8[i + 4] = (bf16)u1[i]; }
        *(bf16x8*)(ks + c) = k8;
      }
    }
    // stage V tile transposed -> Vt[d][n]
    {
      const float* vg = V + (size_t)(n0 + vn) * DD + vd0;
#pragma unroll
      for (int dd = 0; dd < 24; dd++) Vt[(vd0 + dd) * 72 + vn] = (bf16)vg[dd];
    }
    __syncthreads();

    // S = Q K^T : wave's 16 rows x 64 cols
    floatx4 s4[4];
#pragma unroll
    for (int j = 0; j < 4; j++) {
      floatx4 sa = {0, 0, 0, 0};
#pragma unroll
      for (int c = 0; c < 3; c++) {
        bf16x8 kf = *(const bf16x8*)&Ks[(j * 16 + fr) * 104 + c * 32 + quad * 8];
        sa = __builtin_amdgcn_mfma_f32_16x16x32_bf16(qf[c], kf, sa, 0, 0, 0);
      }
      s4[j] = sa;
    }
    // bias + online softmax
    float kxx[4], kyy[4];
#pragma unroll
    for (int j = 0; j < 4; j++) {
      int ki = (n0 + j * 16 + fr) * 2;
      kxx[j] = kp[ki];
      kyy[j] = kp[ki + 1];
    }
    float p[4][4], rmax[4], rsum[4], alpha[4];
#pragma unroll
    for (int r = 0; r < 4; r++) rmax[r] = -1e30f;
#pragma unroll
    for (int j = 0; j < 4; j++)
#pragma unroll
      for (int r = 0; r < 4; r++) {
        float dx = qx[r] - kxx[j], dy = qy[r] - kyy[j];
        float sv = s4[j][r] * ATT_SCALE - 2.0f * (dx * dx + dy * dy);
        p[j][r] = sv;
        rmax[r] = fmaxf(rmax[r], sv);
      }
#pragma unroll
    for (int r = 0; r < 4; r++) {
#pragma unroll
      for (int o = 1; o < 16; o <<= 1) rmax[r] = fmaxf(rmax[r], __shfl_xor(rmax[r], o));
      float mnew = fmaxf(mrow[r], rmax[r]);
      alpha[r] = __expf(mrow[r] - mnew);
      mrow[r] = mnew;
      rsum[r] = 0.f;
    }
#pragma unroll
    for (int j = 0; j < 4; j++)
#pragma unroll
      for (int r = 0; r < 4; r++) {
        float pv = __expf(p[j][r] - mrow[r]);
        p[j][r] = pv;
        rsum[r] += pv;
      }
#pragma unroll
    for (int r = 0; r < 4; r++) {
#pragma unroll
      for (int o = 1; o < 16; o <<= 1) rsum[r] += __shfl_xor(rsum[r], o);
      lrow[r] = lrow[r] * alpha[r] + rsum[r];
    }
    // P -> LDS (C-layout writes), read back in A-layout; rescale O
#pragma unroll
    for (int j = 0; j < 4; j++)
#pragma unroll
      for (int r = 0; r < 4; r++)
        Ps[(w * 16 + quad * 4 + r) * 72 + j * 16 + fr] = (bf16)p[j][r];
#pragma unroll
    for (int d = 0; d < 6; d++)
#pragma unroll
      for (int r = 0; r < 4; r++) oacc[d][r] *= alpha[r];
    bf16x8 pf0 = *(const bf16x8*)&Ps[(w * 16 + fr) * 72 + quad * 8];
    bf16x8 pf1 = *(const bf16x8*)&Ps[(w * 16 + fr) * 72 + 32 + quad * 8];
#pragma unroll
    for (int d = 0; d < 6; d++) {
      bf16x8 v0 = *(const bf16x8*)&Vt[(d * 16 + fr) * 72 + quad * 8];
      bf16x8 v1 = *(const bf16x8*)&Vt[(d * 16 + fr) * 72 + 32 + quad * 8];
      oacc[d] = __builtin_amdgcn_mfma_f32_16x16x32_bf16(pf0, v0, oacc[d], 0, 0, 0);
      oacc[d] = __builtin_amdgcn_mfma_f32_16x16x32_bf16(pf1, v1, oacc[d], 0, 0, 0);
    }
  }
  // epilogue: O / l
#pragma unroll
  for (int r = 0; r < 4; r++) {
    float inv = 1.0f / lrow[r];
    int row = q0 + w * 16 + quad * 4 + r;
#pragma unroll
    for (int d = 0; d < 6; d++)
      O[(size_t)row * DD + d * 16 + fr] = oacc[d][r] * inv;
  }
}

// ---------------------------------------------------------------- launch
extern "C" void kernel_launch(void* const* d_in, const int* in_sizes, int n_in,
                              void* d_out, int out_size, void* d_ws, size_t ws_size,
                              hipStream_t stream) {
  const float* features = (const float*)d_in[0];
  const float* tracks   = (const float*)d_in[1];
  const float* fpos     = (const float*)d_in[2];
  const float* tpe      = (const float*)d_in[3];
  const float* fpe      = (const float*)d_in[4];
  const float* Wq_s     = (const float*)d_in[5];
  const float* Wk_s     = (const float*)d_in[6];
  const float* Wv_s     = (const float*)d_in[7];
  const float* qg_s     = (const float*)d_in[8];
  const float* kg_s     = (const float*)d_in[9];
  const float* Wo_s     = (const float*)d_in[10];
  const float* Wq_p     = (const float*)d_in[11];
  const float* Wk_p     = (const float*)d_in[12];
  const float* Wv_p     = (const float*)d_in[13];
  const float* qg_p     = (const float*)d_in[14];
  const float* kg_p     = (const float*)d_in[15];
  const float* Wout_p   = (const float*)d_in[16];
  float* out = (float*)d_out;

  const size_t Sb = (size_t)16 * 1024 * 768;  // 12,582,912 floats
  const size_t Ss = (size_t)16 * 256 * 768;   //  3,145,728 floats
  float* B0 = (float*)d_ws;   // big buffer 0
  float* B1 = B0 + Sb;        // big buffer 1
  float* s0 = B1 + Sb;        // small buffers
  float* s1 = s0 + Ss;
  float* s2 = s1 + Ss;

  dim3 blk(256);

  // X = features + fpe -> B0
  add_kernel<<<2048, blk, 0, stream>>>(features, fpe, B0, (int)(Sb / 4));
  // K_s = LN(X @ Wk_s^T) -> B1
  gemm_bt<<<dim3(256, 12), blk, 0, stream>>>(B0, Wk_s, B1, nullptr);
  ln_kernel<<<16384, blk, 0, stream>>>(B1, kg_s);
  // V_s = features @ Wv_s^T -> B0 (X no longer needed)
  gemm_bt<<<dim3(256, 12), blk, 0, stream>>>(features, Wv_s, B0, nullptr);
  // Q_s = LN(tpe @ Wq_s^T) -> s0
  gemm_bt<<<dim3(64, 12), blk, 0, stream>>>(tpe, Wq_s, s0, nullptr);
  ln_kernel<<<4096, blk, 0, stream>>>(s0, qg_s);
  // sampled_h = attn(Q_s, K_s, V_s, bias) -> s1   (tracks query pixels)
  attn_kernel<<<dim3(4, 8, 16), blk, 0, stream>>>(s0, B1, B0, s1,
                                                  tracks, 512, fpos, 0, 256, 1024);
  // sampled = sampled_h @ Wo_s^T -> s2
  gemm_bt<<<dim3(64, 12), blk, 0, stream>>>(s1, Wo_s, s2, nullptr);
  // Q2 = LN(fpe @ Wq_p^T) -> B0
  gemm_bt<<<dim3(256, 12), blk, 0, stream>>>(fpe, Wq_p, B0, nullptr);
  ln_kernel<<<16384, blk, 0, stream>>>(B0, qg_p);
  // K2 = LN(tpe @ Wk_p^T) -> s0
  gemm_bt<<<dim3(64, 12), blk, 0, stream>>>(tpe, Wk_p, s0, nullptr);
  ln_kernel<<<4096, blk, 0, stream>>>(s0, kg_p);
  // V2 = sampled @ Wv_p^T -> s1
  gemm_bt<<<dim3(64, 12), blk, 0, stream>>>(s2, Wv_p, s1, nullptr);
  // upd_h = attn(Q2, K2, V2, bias^T) -> B1   (pixels query tracks)
  attn_kernel<<<dim3(16, 8, 16), blk, 0, stream>>>(B0, s0, s1, B1,
                                                   fpos, 0, tracks, 512, 1024, 256);
  // out = features + upd_h @ Wout_p^T
  gemm_bt<<<dim3(256, 12), blk, 0, stream>>>(B1, Wout_p, out, features);
}

// Round 2
// 531.508 us; speedup vs baseline: 1.5192x; 1.5192x over previous
//
#include <hip/hip_runtime.h>

#define DD 768
#define HDIM 96
#define ATT_SCALE 0.10206207261596575f  // 1/sqrt(96)

typedef float floatx4 __attribute__((ext_vector_type(4)));
typedef __bf16 bf16;
typedef bf16 bf16x8 __attribute__((ext_vector_type(8)));
typedef bf16 bf16x4 __attribute__((ext_vector_type(4)));

__device__ __forceinline__ void gl2lds16(const bf16* g, bf16* l) {
  __builtin_amdgcn_global_load_lds(
      (const __attribute__((address_space(1))) void*)g,
      (__attribute__((address_space(3))) void*)l, 16, 0, 0);
}

// ------------------------------------------------ conversions (fp32 -> bf16)
// features, fpe -> features_bf16, (features+fpe)_bf16, fpe_bf16 in one pass
__global__ __launch_bounds__(256) void conv_fuse(const float* __restrict__ f,
                                                 const float* __restrict__ e,
                                                 bf16* __restrict__ fb,
                                                 bf16* __restrict__ xb,
                                                 bf16* __restrict__ eb) {
  const int i = (blockIdx.x * 256 + threadIdx.x) * 8;
  floatx4 f0 = *(const floatx4*)(f + i);
  floatx4 f1 = *(const floatx4*)(f + i + 4);
  floatx4 e0 = *(const floatx4*)(e + i);
  floatx4 e1 = *(const floatx4*)(e + i + 4);
  bf16x8 fv, xv, ev;
#pragma unroll
  for (int k = 0; k < 4; k++) {
    fv[k] = (bf16)f0[k];           fv[k + 4] = (bf16)f1[k];
    ev[k] = (bf16)e0[k];           ev[k + 4] = (bf16)e1[k];
    xv[k] = (bf16)(f0[k] + e0[k]); xv[k + 4] = (bf16)(f1[k] + e1[k]);
  }
  *(bf16x8*)(fb + i) = fv;
  *(bf16x8*)(xb + i) = xv;
  *(bf16x8*)(eb + i) = ev;
}

__global__ __launch_bounds__(256) void f2b(const float* __restrict__ s,
                                           bf16* __restrict__ d) {
  const int i = (blockIdx.x * 256 + threadIdx.x) * 8;
  floatx4 s0 = *(const floatx4*)(s + i);
  floatx4 s1 = *(const floatx4*)(s + i + 4);
  bf16x8 v;
#pragma unroll
  for (int k = 0; k < 4; k++) { v[k] = (bf16)s0[k]; v[k + 4] = (bf16)s1[k]; }
  *(bf16x8*)(d + i) = v;
}

// 8 weight matrices of 768*768 each -> contiguous bf16
__global__ __launch_bounds__(256) void wconv(const float* w0, const float* w1,
                                             const float* w2, const float* w3,
                                             const float* w4, const float* w5,
                                             const float* w6, const float* w7,
                                             bf16* __restrict__ dst) {
  const float* srcs[8] = {w0, w1, w2, w3, w4, w5, w6, w7};
  const float* s = srcs[blockIdx.y];
  bf16* d = dst + (size_t)blockIdx.y * 589824;
  const int i = (blockIdx.x * 256 + threadIdx.x) * 8;
  floatx4 s0 = *(const floatx4*)(s + i);
  floatx4 s1 = *(const floatx4*)(s + i + 4);
  bf16x8 v;
#pragma unroll
  for (int k = 0; k < 4; k++) { v[k] = (bf16)s0[k]; v[k + 4] = (bf16)s1[k]; }
  *(bf16x8*)(d + i) = v;
}

// ------------------------------------------------ LayerNorm on bf16, in place
// one wave per row of 768; fp32 stats; gain g fp32
__global__ __launch_bounds__(256) void ln_bf(bf16* __restrict__ X,
                                             const float* __restrict__ g) {
  const int w = threadIdx.x >> 6, lane = threadIdx.x & 63;
  bf16* x = X + (size_t)(blockIdx.x * 4 + w) * DD;
  float v[12], s = 0.f, ss = 0.f;
#pragma unroll
  for (int j = 0; j < 3; j++) {
    bf16x4 b = *(const bf16x4*)&x[j * 256 + lane * 4];
#pragma unroll
    for (int e = 0; e < 4; e++) {
      float t = (float)b[e];
      v[j * 4 + e] = t; s += t; ss += t * t;
    }
  }
#pragma unroll
  for (int o = 32; o > 0; o >>= 1) { s += __shfl_xor(s, o); ss += __shfl_xor(ss, o); }
  const float mean = s * (1.0f / DD);
  const float inv = rsqrtf(ss * (1.0f / DD) - mean * mean + 1e-6f);
#pragma unroll
  for (int j = 0; j < 3; j++) {
    floatx4 gg = *(const floatx4*)&g[j * 256 + lane * 4];
    bf16x4 o4;
#pragma unroll
    for (int e = 0; e < 4; e++) o4[e] = (bf16)((v[j * 4 + e] - mean) * inv * gg[e]);
    *(bf16x4*)&x[j * 256 + lane * 4] = o4;
  }
}

// ------------------------------------------------ GEMM  C = A @ W^T  (m97 structure)
// A [M,768] bf16, W [768,768] bf16 (row = out channel), 128x128 tile, BK=32,
// global_load_lds width 16, unpadded LDS [128][32].
// MODE 0: C bf16.  MODE 1: C fp32 = acc + addsrc.
template <int MODE>
__global__ __launch_bounds__(256) void gemm128(const bf16* __restrict__ A,
                                               const bf16* __restrict__ W,
                                               bf16* __restrict__ Cb,
                                               float* __restrict__ Cf,
                                               const float* __restrict__ addsrc) {
  __shared__ bf16 As[128 * 32];
  __shared__ bf16 Ws[128 * 32];
  const int tid = threadIdx.x;
  const int lane = tid & 63;
  const int w = tid >> 6;
  const int row0 = blockIdx.x * 128;
  const int col0 = blockIdx.y * 128;
  const int wm = (w & 1) * 64;
  const int wn = (w >> 1) * 64;
  const int fr = lane & 15;
  const int quad = lane >> 4;
  // staging: issue i covers rows i*64..i*64+63; this thread -> row i*64 + tid/4, col (tid&3)*8
  const int srow = tid >> 2;
  const int scol = (tid & 3) * 8;
  const bf16* Ag = A + (size_t)(row0 + srow) * DD + scol;
  const bf16* Wg = W + (size_t)(col0 + srow) * DD + scol;
  bf16* AsD = &As[tid * 8];  // lane-order dest: tid*16 bytes
  bf16* WsD = &Ws[tid * 8];

  floatx4 acc[4][4];
#pragma unroll
  for (int i = 0; i < 4; i++)
#pragma unroll
    for (int j = 0; j < 4; j++) acc[i][j] = (floatx4){0, 0, 0, 0};

  for (int k0 = 0; k0 < DD; k0 += 32) {
    __syncthreads();
    gl2lds16(Ag + k0, AsD);
    gl2lds16(Ag + k0 + (size_t)64 * DD, AsD + 2048);
    gl2lds16(Wg + k0, WsD);
    gl2lds16(Wg + k0 + (size_t)64 * DD, WsD + 2048);
    __syncthreads();
    bf16x8 af[4], bfr[4];
#pragma unroll
    for (int i = 0; i < 4; i++)
      af[i] = *(const bf16x8*)&As[(wm + i * 16 + fr) * 32 + quad * 8];
#pragma unroll
    for (int j = 0; j < 4; j++)
      bfr[j] = *(const bf16x8*)&Ws[(wn + j * 16 + fr) * 32 + quad * 8];
#pragma unroll
    for (int i = 0; i < 4; i++)
#pragma unroll
      for (int j = 0; j < 4; j++)
        acc[i][j] = __builtin_amdgcn_mfma_f32_16x16x32_bf16(af[i], bfr[j], acc[i][j], 0, 0, 0);
  }
  // epilogue: C/D layout col=lane&15, row=quad*4+r
#pragma unroll
  for (int i = 0; i < 4; i++)
#pragma unroll
    for (int j = 0; j < 4; j++)
#pragma unroll
      for (int r = 0; r < 4; r++) {
        const int row = row0 + wm + i * 16 + quad * 4 + r;
        const int col = col0 + wn + j * 16 + fr;
        const size_t idx = (size_t)row * DD + col;
        if (MODE == 0) Cb[idx] = (bf16)acc[i][j][r];
        else Cf[idx] = acc[i][j][r] + addsrc[idx];
      }
}

// ------------------------------------------------ fused attention (bf16 I/O)
// Per (t, h, 64-query tile): O = softmax(Q K^T * scale - 2*d2) V, head slice h*96.
__global__ __launch_bounds__(256) void attn_kernel(
    const bf16* __restrict__ Qb, const bf16* __restrict__ Kb,
    const bf16* __restrict__ Vb, bf16* __restrict__ Ob,
    const float* __restrict__ qpos, int qpos_ts,
    const float* __restrict__ kpos, int kpos_ts,
    int nq, int nk) {
  const int t = blockIdx.z, h = blockIdx.y;
  const int q0 = blockIdx.x * 64;
  const bf16* Q = Qb + (size_t)t * nq * DD + h * HDIM;
  const bf16* K = Kb + (size_t)t * nk * DD + h * HDIM;
  const bf16* V = Vb + (size_t)t * nk * DD + h * HDIM;
  bf16* O = Ob + (size_t)t * nq * DD + h * HDIM;
  const float* qp = qpos + (size_t)t * qpos_ts;
  const float* kp = kpos + (size_t)t * kpos_ts;

  __shared__ bf16 Ks[64 * 104];  // [n][k] stride 104
  __shared__ bf16 Vt[96 * 72];   // [d][n] stride 72 (B-operand of P*V)
  __shared__ bf16 Ps[64 * 72];   // [m][n]

  const int tid = threadIdx.x;
  const int w = tid >> 6;
  const int lane = tid & 63;
  const int fr = lane & 15;
  const int quad = lane >> 4;

  // Q fragments (A-layout: A[m=lane&15][k=quad*8+j])
  bf16x8 qf[3];
  {
    const bf16* qrow = Q + (size_t)(q0 + w * 16 + fr) * DD;
#pragma unroll
    for (int c = 0; c < 3; c++) qf[c] = *(const bf16x8*)(qrow + c * 32 + quad * 8);
  }
  float qx[4], qy[4];
#pragma unroll
  for (int r = 0; r < 4; r++) {
    int qi = q0 + w * 16 + quad * 4 + r;
    qx[r] = qp[qi * 2];
    qy[r] = qp[qi * 2 + 1];
  }

  float mrow[4], lrow[4];
  floatx4 oacc[6];
#pragma unroll
  for (int r = 0; r < 4; r++) { mrow[r] = -1e30f; lrow[r] = 0.f; }
#pragma unroll
  for (int d = 0; d < 6; d++) oacc[d] = (floatx4){0, 0, 0, 0};

  const int srow = tid >> 2, scol = (tid & 3) * 24;
  const int vn = tid & 63, vd0 = (tid >> 6) * 24;

  for (int n0 = 0; n0 < nk; n0 += 64) {
    __syncthreads();
    {  // K tile [64][96]
      const bf16* kg = K + (size_t)(n0 + srow) * DD + scol;
      bf16* ks = &Ks[srow * 104 + scol];
#pragma unroll
      for (int c = 0; c < 3; c++) *(bf16x8*)(ks + c * 8) = *(const bf16x8*)(kg + c * 8);
    }
    {  // V tile transposed -> Vt[d][n]
      const bf16* vg = V + (size_t)(n0 + vn) * DD + vd0;
      bf16x8 v8[3];
#pragma unroll
      for (int c = 0; c < 3; c++) v8[c] = *(const bf16x8*)(vg + c * 8);
#pragma unroll
      for (int dd = 0; dd < 24; dd++) Vt[(vd0 + dd) * 72 + vn] = v8[dd >> 3][dd & 7];
    }
    __syncthreads();

    // S = Q K^T : wave's 16 rows x 64 cols
    floatx4 s4[4];
#pragma unroll
    for (int j = 0; j < 4; j++) {
      floatx4 sa = {0, 0, 0, 0};
#pragma unroll
      for (int c = 0; c < 3; c++) {
        bf16x8 kf = *(const bf16x8*)&Ks[(j * 16 + fr) * 104 + c * 32 + quad * 8];
        sa = __builtin_amdgcn_mfma_f32_16x16x32_bf16(qf[c], kf, sa, 0, 0, 0);
      }
      s4[j] = sa;
    }
    float kxx[4], kyy[4];
#pragma unroll
    for (int j = 0; j < 4; j++) {
      int ki = (n0 + j * 16 + fr) * 2;
      kxx[j] = kp[ki];
      kyy[j] = kp[ki + 1];
    }
    float p[4][4], rmax[4], rsum[4], alpha[4];
#pragma unroll
    for (int r = 0; r < 4; r++) rmax[r] = -1e30f;
#pragma unroll
    for (int j = 0; j < 4; j++)
#pragma unroll
      for (int r = 0; r < 4; r++) {
        float dx = qx[r] - kxx[j], dy = qy[r] - kyy[j];
        float sv = s4[j][r] * ATT_SCALE - 2.0f * (dx * dx + dy * dy);
        p[j][r] = sv;
        rmax[r] = fmaxf(rmax[r], sv);
      }
#pragma unroll
    for (int r = 0; r < 4; r++) {
#pragma unroll
      for (int o = 1; o < 16; o <<= 1) rmax[r] = fmaxf(rmax[r], __shfl_xor(rmax[r], o));
      float mnew = fmaxf(mrow[r], rmax[r]);
      alpha[r] = __expf(mrow[r] - mnew);
      mrow[r] = mnew;
      rsum[r] = 0.f;
    }
#pragma unroll
    for (int j = 0; j < 4; j++)
#pragma unroll
      for (int r = 0; r < 4; r++) {
        float pv = __expf(p[j][r] - mrow[r]);
        p[j][r] = pv;
        rsum[r] += pv;
      }
#pragma unroll
    for (int r = 0; r < 4; r++) {
#pragma unroll
      for (int o = 1; o < 16; o <<= 1) rsum[r] += __shfl_xor(rsum[r], o);
      lrow[r] = lrow[r] * alpha[r] + rsum[r];
    }
#pragma unroll
    for (int j = 0; j < 4; j++)
#pragma unroll
      for (int r = 0; r < 4; r++)
        Ps[(w * 16 + quad * 4 + r) * 72 + j * 16 + fr] = (bf16)p[j][r];
#pragma unroll
    for (int d = 0; d < 6; d++)
#pragma unroll
      for (int r = 0; r < 4; r++) oacc[d][r] *= alpha[r];
    bf16x8 pf0 = *(const bf16x8*)&Ps[(w * 16 + fr) * 72 + quad * 8];
    bf16x8 pf1 = *(const bf16x8*)&Ps[(w * 16 + fr) * 72 + 32 + quad * 8];
#pragma unroll
    for (int d = 0; d < 6; d++) {
      bf16x8 v0 = *(const bf16x8*)&Vt[(d * 16 + fr) * 72 + quad * 8];
      bf16x8 v1 = *(const bf16x8*)&Vt[(d * 16 + fr) * 72 + 32 + quad * 8];
      oacc[d] = __builtin_amdgcn_mfma_f32_16x16x32_bf16(pf0, v0, oacc[d], 0, 0, 0);
      oacc[d] = __builtin_amdgcn_mfma_f32_16x16x32_bf16(pf1, v1, oacc[d], 0, 0, 0);
    }
  }
#pragma unroll
  for (int r = 0; r < 4; r++) {
    float inv = 1.0f / lrow[r];
    int row = q0 + w * 16 + quad * 4 + r;
#pragma unroll
    for (int d = 0; d < 6; d++)
      O[(size_t)row * DD + d * 16 + fr] = (bf16)(oacc[d][r] * inv);
  }
}

// ------------------------------------------------ launch
extern "C" void kernel_launch(void* const* d_in, const int* in_sizes, int n_in,
                              void* d_out, int out_size, void* d_ws, size_t ws_size,
                              hipStream_t stream) {
  const float* features = (const float*)d_in[0];
  const float* tracks   = (const float*)d_in[1];
  const float* fpos     = (const float*)d_in[2];
  const float* tpe      = (const float*)d_in[3];
  const float* fpe      = (const float*)d_in[4];
  const float* Wq_s     = (const float*)d_in[5];
  const float* Wk_s     = (const float*)d_in[6];
  const float* Wv_s     = (const float*)d_in[7];
  const float* qg_s     = (const float*)d_in[8];
  const float* kg_s     = (const float*)d_in[9];
  const float* Wo_s     = (const float*)d_in[10];
  const float* Wq_p     = (const float*)d_in[11];
  const float* Wk_p     = (const float*)d_in[12];
  const float* Wv_p     = (const float*)d_in[13];
  const float* qg_p     = (const float*)d_in[14];
  const float* kg_p     = (const float*)d_in[15];
  const float* Wout_p   = (const float*)d_in[16];
  float* out = (float*)d_out;

  const size_t SB = (size_t)16 * 1024 * 768;  // 12,582,912
  const size_t SS = (size_t)16 * 256 * 768;   //  3,145,728
  const size_t SW = (size_t)768 * 768;        //    589,824
  bf16* p = (bf16*)d_ws;
  bf16* Fb  = p; p += SB;   // features bf16
  bf16* Xb  = p; p += SB;   // features+fpe bf16 (later reused as Q2)
  bf16* Feb = p; p += SB;   // fpe bf16
  bf16* Kc  = p; p += SB;   // K_s
  bf16* Vc  = p; p += SB;   // V_s
  bf16* Tb  = p; p += SS;   // tpe bf16
  bf16* Qc  = p; p += SS;   // Q_s (later reused as K2)
  bf16* Sh  = p; p += SS;   // sampled heads (later reused as V2)
  bf16* Sp  = p; p += SS;   // sampled
  bf16* Wb  = p; p += 8 * SW;
  bf16* Q2 = Xb; bf16* K2 = Qc; bf16* V2 = Sh; bf16* U = Fb;

  dim3 blk(256);

  conv_fuse<<<6144, blk, 0, stream>>>(features, fpe, Fb, Xb, Feb);
  f2b<<<1536, blk, 0, stream>>>(tpe, Tb);
  wconv<<<dim3(288, 8), blk, 0, stream>>>(Wq_s, Wk_s, Wv_s, Wo_s,
                                          Wq_p, Wk_p, Wv_p, Wout_p, Wb);
  // ---- sampling path ----
  gemm128<0><<<dim3(128, 6), blk, 0, stream>>>(Xb, Wb + 1 * SW, Kc, nullptr, nullptr);
  ln_bf<<<4096, blk, 0, stream>>>(Kc, kg_s);
  gemm128<0><<<dim3(128, 6), blk, 0, stream>>>(Fb, Wb + 2 * SW, Vc, nullptr, nullptr);
  gemm128<0><<<dim3(32, 6), blk, 0, stream>>>(Tb, Wb + 0 * SW, Qc, nullptr, nullptr);
  ln_bf<<<1024, blk, 0, stream>>>(Qc, qg_s);
  attn_kernel<<<dim3(4, 8, 16), blk, 0, stream>>>(Qc, Kc, Vc, Sh,
                                                  tracks, 512, fpos, 0, 256, 1024);
  gemm128<0><<<dim3(32, 6), blk, 0, stream>>>(Sh, Wb + 3 * SW, Sp, nullptr, nullptr);
  // ---- splatting path ----
  gemm128<0><<<dim3(128, 6), blk, 0, stream>>>(Feb, Wb + 4 * SW, Q2, nullptr, nullptr);
  ln_bf<<<4096, blk, 0, stream>>>(Q2, qg_p);
  gemm128<0><<<dim3(32, 6), blk, 0, stream>>>(Tb, Wb + 5 * SW, K2, nullptr, nullptr);
  ln_bf<<<1024, blk, 0, stream>>>(K2, kg_p);
  gemm128<0><<<dim3(32, 6), blk, 0, stream>>>(Sp, Wb + 6 * SW, V2, nullptr, nullptr);
  attn_kernel<<<dim3(16, 8, 16), blk, 0, stream>>>(Q2, K2, V2, U,
                                                   fpos, 0, tracks, 512, 1024, 256);
  gemm128<1><<<dim3(128, 6), blk, 0, stream>>>(U, Wb + 7 * SW, nullptr, out, features);
}